// Round 9
// baseline (200.849 us; speedup 1.0000x reference)
//
#include <hip/hip_runtime.h>
#include <math.h>

#define D_MODEL 1024
#define N_HEADS 16
#define D_HEAD  64
#define B_SZ    2
#define T_SEQ   2048
#define WN_ELEMS (1024u * 1024u)

typedef short bf16x8 __attribute__((ext_vector_type(8)));
typedef short bf16x4 __attribute__((ext_vector_type(4)));
typedef float f32x4  __attribute__((ext_vector_type(4)));
typedef unsigned short us4 __attribute__((ext_vector_type(4)));

// fp32 -> bf16 (RNE)
__device__ __forceinline__ unsigned short f2bf(float f) {
  union { float f; unsigned u; } v; v.f = f;
  unsigned r = v.u + 0x7FFFu + ((v.u >> 16) & 1u);
  return (unsigned short)(r >> 16);
}
// bf16 -> fp32
__device__ __forceinline__ float bf2f(unsigned short s) {
  union { unsigned u; float f; } v; v.u = ((unsigned)s) << 16;
  return v.f;
}
// pack two fp32 -> bf16x2 (RTZ) in one v_perm_b32
__device__ __forceinline__ unsigned pack2_rtz(float lo, float hi) {
  union { float f; unsigned u; } a, b; a.f = hi; b.f = lo;
  return __builtin_amdgcn_perm(a.u, b.u, 0x07060302u);
}

// async global->LDS, 16B per lane. LDS dest = wave-uniform base + lane*16.
__device__ __forceinline__ void async_copy16(const unsigned short* g, unsigned short* l) {
  __builtin_amdgcn_global_load_lds(
      (__attribute__((address_space(1))) void*)(g),
      (__attribute__((address_space(3))) void*)(l), 16, 0, 0);
}

// Fragment-major W layout: for feature row n, contraction col k:
//   fb=n>>5, mi=(n>>4)&1, lr=n&15, kt=k>>6, hf=(k>>5)&1, quad=(k>>3)&3, e=k&7
//   idx = (fb*16+kt)*2048 + (mi*2+hf)*512 + (quad*16+lr)*8 + e
// -> a wave's MFMA fragment load is ONE fully-coalesced 1KB read.
__device__ __forceinline__ size_t widx(int n, int k) {
  const int fb = n >> 5, mi = (n >> 4) & 1, lr = n & 15;
  const int kt = k >> 6, hf = (k >> 5) & 1, quad = (k >> 3) & 3, e = k & 7;
  return ((size_t)(fb * 16 + kt) * 4 + (mi * 2 + hf)) * 512 + (quad * 16 + lr) * 8 + e;
}

// Opart split-region: p-th 4KB partial lives in wt[0..3WN) (dead after
// qkv_gemm) for p < 1536, else in xb (dead after qkv_gemm).
__device__ __forceinline__ unsigned short* opart_ptr(
    unsigned short* wtd, unsigned short* xbd, int p) {
  const size_t off = (size_t)p * 2048;
  const size_t RA  = (size_t)3 * 1024 * 1024;   // 3WN elems (6 MiB)
  return (off < RA) ? (wtd + off) : (xbd + (off - RA));
}

// ---------------------------------------------------------------------------
// Fused converts. grid (32,32,8): z<4 -> W[z] fp32[K,N] -> wt bf16
// FRAGMENT-MAJOR (widx); z>=4 -> x fp32 -> bf16 rows.
// ---------------------------------------------------------------------------
__global__ __launch_bounds__(256) void conv_all(
    const float* __restrict__ x,
    const float* __restrict__ wq, const float* __restrict__ wk,
    const float* __restrict__ wv, const float* __restrict__ wo,
    unsigned short* __restrict__ wt, unsigned short* __restrict__ xb)
{
  const int z = blockIdx.z;
  if (z < 4) {
    const float* W = (z == 0) ? wq : (z == 1) ? wk : (z == 2) ? wv : wo;
    unsigned short* O = wt + (size_t)z * WN_ELEMS;
    __shared__ float t[32][33];
    const int tx = threadIdx.x & 31, ty = threadIdx.x >> 5;
    const int kb = blockIdx.x * 32, nb = blockIdx.y * 32;
    #pragma unroll
    for (int i = 0; i < 4; i++)
      t[ty + i * 8][tx] = W[(size_t)(kb + ty + i * 8) * D_MODEL + nb + tx];
    __syncthreads();
    #pragma unroll
    for (int i = 0; i < 4; i++)
      O[widx(nb + ty + i * 8, kb + tx)] = f2bf(t[tx][ty + i * 8]);
  } else {
    const int row = (z - 4) * 1024 + blockIdx.y * 32 + (threadIdx.x >> 3);
    const int col = blockIdx.x * 32 + (threadIdx.x & 7) * 4;
    float4 v = *(const float4*)&x[(size_t)row * D_MODEL + col];
    us4 o = { f2bf(v.x), f2bf(v.y), f2bf(v.z), f2bf(v.w) };
    *(us4*)&xb[(size_t)row * D_MODEL + col] = o;
  }
}

// ---------------------------------------------------------------------------
// Fused QKV GEMM, R8: 128(token) x 128(feature, SAME mid) tiles, grid
// (32,24) = 768 blocks. Waves 1x4 over features: each wave owns 32 feat x
// ALL 128 tokens -> 32 MFMA/wave/K-step (2x R7) against the same 16KB x
// stage, so per-step compute (~350cy) now covers the L2 staging latency
// (~300-500cy) that R1-R7 showed was the binder (all pipes <25% at 43us,
// invariant to occupancy/dbuf/traffic/LDS-bytes). Also halves x panel
// re-reads (48->24). W: in-step global->VGPR from fragment-major layout
// (4 coalesced 1KB loads, issued BEFORE stage(t+1) so the compiler's
// auto-wait before MFMA is vmcnt(4): W waited, stage left in flight).
// NOTE: Q is pre-scaled by 0.125*log2(e) here so flash softmax is exp2(s).
// ---------------------------------------------------------------------------
#define BKg 64
#define NTg (D_MODEL / BKg)   /* 16 K-steps */
#define QSCALE 0.180336879f   /* 0.125 * log2(e) */

__global__ __launch_bounds__(256) void qkv_gemm(
    const unsigned short* __restrict__ A, const unsigned short* __restrict__ Bt,
    const float* __restrict__ bq, const float* __restrict__ bk,
    const float* __restrict__ bv, unsigned short* __restrict__ qkv,
    unsigned short* __restrict__ vT)
{
  __shared__ unsigned short As[2][128 * BKg];   // x tiles: 2x16 KB

  const int tid  = threadIdx.x;
  const int wv   = tid >> 6;           // wave 0..3 = feature quarter
  const int lane = tid & 63;
  const int lr   = lane & 15;
  const int quad = lane >> 4;
  const int row0 = blockIdx.x * 128;   // tokens
  const int col0 = blockIdx.y * 128;   // global feature col in [0,3072)
  const int colL = col0 & 1023;        // within-mid feature base
  const int K = D_MODEL;

  const int mid = col0 >> 10;                       // 0=q,1=k,2=v
  const float* bias = (mid == 0) ? bq : (mid == 1) ? bk : bv;

  f32x4 acc[16];
  #pragma unroll
  for (int i = 0; i < 16; i++) acc[i] = (f32x4){0.f, 0.f, 0.f, 0.f};

  auto stageA = [&](int buf, int k0) {
    #pragma unroll
    for (int it = 0; it < 4; it++) {
      const int gg = wv * 256 + it * 64 + lane;
      const int r  = gg >> 3;
      const int gc = ((gg & 7) ^ (r & 7)) * 8;
      async_copy16(A + (size_t)(row0 + r) * K + k0 + gc,
                   &As[buf][(size_t)(wv * 256 + it * 64) * 8]);
    }
  };

  // wave's 32-feature block in fragment-major W
  const int fb = (colL >> 5) + wv;
  const unsigned short* Wp =
      Bt + (size_t)mid * WN_ELEMS + (size_t)fb * (16 * 2048) + lane * 8;

  int cur = 0;
  stageA(0, 0);

  for (int t = 0; t < NTg; ++t) {
    __syncthreads();                      // x tile t visible in buffer cur

    // 1) W fragments for this K-step (coalesced 1KB wave loads, to VGPR)
    bf16x8 Wt[2][2];
    #pragma unroll
    for (int mi = 0; mi < 2; mi++)
      #pragma unroll
      for (int hf = 0; hf < 2; hf++)
        Wt[mi][hf] = *(const bf16x8*)&Wp[((size_t)t * 4 + mi * 2 + hf) * 512];

    // 2) x frag ds_reads: all 128 token rows (8 groups of 16)
    bf16x8 xF[8][2];
    #pragma unroll
    for (int hf = 0; hf < 2; hf++) {
      const int kc = ((hf * 4 + quad) ^ (lr & 7)) * 8;
      #pragma unroll
      for (int nt = 0; nt < 8; nt++)
        xF[nt][hf] = *(const bf16x8*)&As[cur][(nt * 16 + lr) * BKg + kc];
    }

    // 3) prefetch x tile t+1 (issued AFTER W loads: MFMA's W-wait = vmcnt(4))
    if (t + 1 < NTg) stageA(cur ^ 1, (t + 1) * BKg);

    // 4) MFMA: 32 per wave per K-step
    if (mid == 2) {
      // A=x (tokens, 8 groups), B=W (features, 2 groups): acc[mi*2+ni]
      #pragma unroll
      for (int hf = 0; hf < 2; hf++)
        #pragma unroll
        for (int mi = 0; mi < 8; mi++)
          #pragma unroll
          for (int ni = 0; ni < 2; ni++)
            acc[mi * 2 + ni] = __builtin_amdgcn_mfma_f32_16x16x32_bf16(
                xF[mi][hf], Wt[ni][hf], acc[mi * 2 + ni], 0, 0, 0);
    } else {
      // A=W (features, 2 groups), B=x (tokens, 8 groups): acc[mi*8+ni]
      #pragma unroll
      for (int hf = 0; hf < 2; hf++)
        #pragma unroll
        for (int mi = 0; mi < 2; mi++)
          #pragma unroll
          for (int ni = 0; ni < 8; ni++)
            acc[mi * 8 + ni] = __builtin_amdgcn_mfma_f32_16x16x32_bf16(
                Wt[mi][hf], xF[ni][hf], acc[mi * 8 + ni], 0, 0, 0);
    }
    cur ^= 1;
  }

  if (mid == 2) {
    // C rows = tokens (mi, quad*4+i), cols = features (ni, lr)
    #pragma unroll
    for (int ni = 0; ni < 2; ni++) {
      const int nn = colL + wv * 32 + ni * 16 + lr;
      const float bv_ = bias[nn];
      const int h = nn >> 6, d = nn & 63;
      #pragma unroll
      for (int mi = 0; mi < 8; mi++) {
        const int t0_ = row0 + mi * 16 + quad * 4;
        const int b = t0_ >> 11, tl = t0_ & 2047;
        us4 o;
        #pragma unroll
        for (int i = 0; i < 4; i++) o[i] = f2bf(acc[mi * 2 + ni][i] + bv_);
        *(us4*)&vT[((size_t)(b * N_HEADS + h) * D_HEAD + d) * T_SEQ + tl] = o;
      }
    }
  } else {
    // C rows = features (mi, quad*4+i), cols = tokens (ni, lr)
    unsigned short* dst = qkv + (size_t)mid * (4096u * 1024u);
    const float qs = (mid == 0) ? QSCALE : 1.0f;   // pre-scale Q for exp2 softmax
    #pragma unroll
    for (int ni = 0; ni < 8; ni++) {
      const int t = row0 + ni * 16 + lr;
      const int b = t >> 11, tl = t & 2047;
      #pragma unroll
      for (int mi = 0; mi < 2; mi++) {
        const int f = colL + wv * 32 + mi * 16 + quad * 4;
        const int h = f >> 6, d = f & 63;
        const float4 b4 = *(const float4*)&bias[f];
        us4 o;
        o[0] = f2bf((acc[mi * 8 + ni][0] + b4.x) * qs);
        o[1] = f2bf((acc[mi * 8 + ni][1] + b4.y) * qs);
        o[2] = f2bf((acc[mi * 8 + ni][2] + b4.z) * qs);
        o[3] = f2bf((acc[mi * 8 + ni][3] + b4.w) * qs);
        *(us4*)&dst[((size_t)(b * N_HEADS + h) * T_SEQ + tl) * D_HEAD + d] = o;
      }
    }
  }
}

// ---------------------------------------------------------------------------
// bf16 MFMA GEMM (O-projection): C = A[M,K] @ W^T + bias[N], fp32 out.
// W (wo) is fragment-major. x LDS dbuf, W global->VGPR coalesced, 2-step
// register pipeline. 128x64 tile -> grid (32,16). (unchanged from R7)
// ---------------------------------------------------------------------------
__global__ __launch_bounds__(256) void mfma_gemm(
    const unsigned short* __restrict__ A, const unsigned short* __restrict__ Bt,
    const float* __restrict__ bias, float* __restrict__ C,
    int M, int N, int K)
{
  __shared__ unsigned short As[2][128 * BKg];   // 2x16 KB

  const int tid  = threadIdx.x;
  const int wv   = tid >> 6;
  const int lane = tid & 63;
  const int lr   = lane & 15;
  const int quad = lane >> 4;
  const int wm   = wv >> 1;
  const int wn   = wv & 1;
  const int row0 = blockIdx.x * 128;
  const int col0 = blockIdx.y * 64;

  f32x4 acc[4][2];
  #pragma unroll
  for (int mi = 0; mi < 4; mi++)
    #pragma unroll
    for (int ni = 0; ni < 2; ni++) acc[mi][ni] = (f32x4){0.f, 0.f, 0.f, 0.f};

  auto stageA = [&](int buf, int k0) {
    #pragma unroll
    for (int it = 0; it < 4; it++) {
      const int gg = wv * 256 + it * 64 + lane;
      const int r  = gg >> 3;
      const int gc = ((gg & 7) ^ (r & 7)) * 8;
      async_copy16(A + (size_t)(row0 + r) * K + k0 + gc,
                   &As[buf][(size_t)(wv * 256 + it * 64) * 8]);
    }
  };

  const int fb = (col0 >> 5) + wn;
  const unsigned short* Wp = Bt + (size_t)fb * (16 * 2048) + lane * 8;
  auto loadW = [&](int kt, bf16x8 (&W)[2][2]) {
    #pragma unroll
    for (int ni = 0; ni < 2; ni++)
      #pragma unroll
      for (int hf = 0; hf < 2; hf++)
        W[ni][hf] = *(const bf16x8*)&Wp[((size_t)kt * 4 + ni * 2 + hf) * 512];
  };

  const int NT = K / BKg;
  bf16x8 Wc[2][2], Wn[2][2];
  loadW(0, Wc);
  stageA(0, 0);
  int cur = 0;

  auto kstep = [&](int t, bf16x8 (&Wuse)[2][2], bf16x8 (&Wpre)[2][2]) {
    __syncthreads();

    bf16x8 aF[4][2];
    #pragma unroll
    for (int hf = 0; hf < 2; hf++) {
      const int kc = ((hf * 4 + quad) ^ (lr & 7)) * 8;
      #pragma unroll
      for (int mi = 0; mi < 4; mi++)
        aF[mi][hf] = *(const bf16x8*)&As[cur][(wm * 64 + mi * 16 + lr) * BKg + kc];
    }

    if (t + 1 < NT) {
      stageA(cur ^ 1, (t + 1) * BKg);
      loadW(t + 1, Wpre);
    }

    #pragma unroll
    for (int hf = 0; hf < 2; hf++)
      #pragma unroll
      for (int mi = 0; mi < 4; mi++)
        #pragma unroll
        for (int ni = 0; ni < 2; ni++)
          acc[mi][ni] = __builtin_amdgcn_mfma_f32_16x16x32_bf16(
              aF[mi][hf], Wuse[ni][hf], acc[mi][ni], 0, 0, 0);
    cur ^= 1;
  };

  #pragma unroll 1
  for (int t = 0; t < NT; t += 2) {
    kstep(t,     Wc, Wn);
    kstep(t + 1, Wn, Wc);
  }

  #pragma unroll
  for (int ni = 0; ni < 2; ni++) {
    const int n = col0 + wn * 32 + ni * 16 + lr;
    const float bv = bias[n];
    #pragma unroll
    for (int mi = 0; mi < 4; mi++) {
      #pragma unroll
      for (int i = 0; i < 4; i++) {
        const int m = row0 + wm * 64 + mi * 16 + quad * 4 + i;
        C[(size_t)m * N + n] = acc[mi][ni][i] + bv;
      }
    }
  }
}

// ---------------------------------------------------------------------------
// LDS-staged S^T flash attention, scale-free softmax (causal), split-KV.
// (unchanged from R7)
// ---------------------------------------------------------------------------
__global__ __launch_bounds__(256) void flash_part(
    const unsigned short* __restrict__ Q, const unsigned short* __restrict__ K,
    const unsigned short* __restrict__ Vt, unsigned short* __restrict__ Out,
    unsigned short* __restrict__ OpA, unsigned short* __restrict__ OpB,
    float* __restrict__ Lpart)
{
  const int bh = blockIdx.x;              // 0..31
  const int y  = blockIdx.y;              // 0..29
  int g, md;                              // md: 0 direct, 1 split-s0, 2 split-s1
  if (y < 28) { g = 15 - (y >> 1); md = 1 + (y & 1); }
  else        { g = 29 - y; md = 0; }     // y=28 -> g=1, y=29 -> g=0

  const int b  = bh >> 4;
  const int h  = bh & 15;

  const unsigned short* Qb = Q  + (size_t)bh * T_SEQ * D_HEAD;
  const unsigned short* Kb = K  + (size_t)bh * T_SEQ * D_HEAD;
  const unsigned short* Vb = Vt + (size_t)bh * D_HEAD * T_SEQ;   // [d][t]

  __shared__ __align__(16) unsigned short Ks[2][64 * 64];
  __shared__ __align__(16) unsigned short Vs[2][64 * 64];

  const int tid  = threadIdx.x;
  const int wv4  = tid >> 6;
  const int lane = tid & 63;
  const int lr   = lane & 15;
  const int quad = lane >> 4;

  const int qg      = 4 * g + wv4;
  const int q0      = qg * 32;
  const int my_full = 2 * g + 1 + (wv4 >> 1);                  // true last tile + 1
  const int tstart  = (md == 2) ? (g + 1) : 0;
  const int bend    = (md == 1) ? (g + 1) : (2 * g + 2);       // block staging range
  const int my_end  = (md == 1) ? (g + 1) : my_full;           // wave compute range

  const int cbase = (tid & ~63);
  const int rr = tid >> 3;                               // 0..31
  const int gcf = ((tid & 7) ^ (rr & 7)) * 8;            // const over it
  const unsigned short* kp0 = Kb + (size_t)rr * D_HEAD + gcf;
  const unsigned short* vp0 = Vb + (size_t)rr * T_SEQ + gcf;

  auto stage = [&](int buf, int tile) {
    const unsigned short* kt = kp0 + (size_t)tile * (64 * D_HEAD);
    const unsigned short* vt = vp0 + (size_t)tile * 64;
    async_copy16(kt,                    &Ks[buf][(size_t)cbase * 8]);
    async_copy16(kt + 32 * D_HEAD,      &Ks[buf][(size_t)(256 + cbase) * 8]);
    async_copy16(vt,                    &Vs[buf][(size_t)cbase * 8]);
    async_copy16(vt + (size_t)32 * T_SEQ, &Vs[buf][(size_t)(256 + cbase) * 8]);
  };

  // Q as B-operand (loop-invariant)
  bf16x8 bQ[2][2];
  #pragma unroll
  for (int qb = 0; qb < 2; qb++)
    #pragma unroll
    for (int kh = 0; kh < 2; kh++)
      bQ[qb][kh] = *(const bf16x8*)&Qb[(size_t)(q0 + qb * 16 + lr) * D_HEAD + kh * 32 + quad * 8];

  f32x4 oacc[2][4];
  #pragma unroll
  for (int qb = 0; qb < 2; qb++)
    #pragma unroll
    for (int dt = 0; dt < 4; dt++) oacc[qb][dt] = (f32x4){0.f, 0.f, 0.f, 0.f};
  f32x4 lacc[2] = {(f32x4){0.f, 0.f, 0.f, 0.f}, (f32x4){0.f, 0.f, 0.f, 0.f}};

  const bf16x4 vONE = {(short)0x3F80, (short)0x3F80, (short)0x3F80, (short)0x3F80};

  int cur = 0;
  stage(0, tstart);

  for (int j = tstart; j < bend; j++) {
    __syncthreads();                        // staged tile j visible
    const bool act = (j < my_end);          // wave-uniform
    const unsigned short* KsB = &Ks[cur][0];
    const unsigned short* VsB = &Vs[cur][0];
    const int kv0 = j * 64;

    // 1) fragment ds_reads of tile j
    bf16x8 aK[4][2];
    bf16x4 aV[4][4];
    if (act) {
      #pragma unroll
      for (int nt = 0; nt < 4; nt++) {
        const int row = nt * 16 + lr;
        #pragma unroll
        for (int kh = 0; kh < 2; kh++) {
          const int sc = (kh * 4 + quad) ^ (row & 7);
          aK[nt][kh] = *(const bf16x8*)&KsB[row * 64 + sc * 8];
        }
      }
      #pragma unroll
      for (int dt = 0; dt < 4; dt++) {
        const int row = dt * 16 + lr;
        #pragma unroll
        for (int ks = 0; ks < 4; ks++) {
          const int sc = (ks * 2 + (quad >> 1)) ^ (row & 7);
          aV[dt][ks] = *(const bf16x4*)&VsB[row * 64 + sc * 8 + (quad & 1) * 4];
        }
      }
    }

    // 2) prefetch next tile into the other buffer (overlaps with compute)
    if (j + 1 < bend) stage(cur ^ 1, j + 1);

    // 3) compute
    if (act) {
      f32x4 sacc[2][4];
      __builtin_amdgcn_s_setprio(1);
      #pragma unroll
      for (int nt = 0; nt < 4; nt++) {
        #pragma unroll
        for (int qb = 0; qb < 2; qb++) {
          f32x4 c = (f32x4){0.f, 0.f, 0.f, 0.f};
          c = __builtin_amdgcn_mfma_f32_16x16x32_bf16(aK[nt][0], bQ[qb][0], c, 0, 0, 0);
          c = __builtin_amdgcn_mfma_f32_16x16x32_bf16(aK[nt][1], bQ[qb][1], c, 0, 0, 0);
          sacc[qb][nt] = c;
        }
      }
      __builtin_amdgcn_s_setprio(0);

      // scale-free softmax: p = exp2(s); Q pre-scaled, no max subtraction
      const bool diag = (j == my_full - 1);
      bf16x4 bP[2][4];
      #pragma unroll
      for (int qb = 0; qb < 2; qb++) {
        if (diag) {
          const int qcol = q0 + qb * 16 + lr;
          #pragma unroll
          for (int nt = 0; nt < 4; nt++)
            #pragma unroll
            for (int i = 0; i < 4; i++)
              if (kv0 + nt * 16 + quad * 4 + i > qcol) sacc[qb][nt][i] = -INFINITY;
        }
        #pragma unroll
        for (int nt = 0; nt < 4; nt++) {
          float p[4];
          #pragma unroll
          for (int i = 0; i < 4; i++)
            p[i] = __builtin_amdgcn_exp2f(sacc[qb][nt][i]);
          union { unsigned u[2]; bf16x4 v; } pk;
          pk.u[0] = pack2_rtz(p[0], p[1]);
          pk.u[1] = pack2_rtz(p[2], p[3]);
          bP[qb][nt] = pk.v;
        }
      }

      // PV + row-sum(l) on the MFMA pipe (ones-fragment matmul)
      __builtin_amdgcn_s_setprio(1);
      #pragma unroll
      for (int ks = 0; ks < 4; ks++) {
        #pragma unroll
        for (int qb = 0; qb < 2; qb++) {
          lacc[qb] = __builtin_amdgcn_mfma_f32_16x16x16bf16_1k(
              vONE, bP[qb][ks], lacc[qb], 0, 0, 0);
          #pragma unroll
          for (int dt = 0; dt < 4; dt++)
            oacc[qb][dt] = __builtin_amdgcn_mfma_f32_16x16x16bf16_1k(
                aV[dt][ks], bP[qb][ks], oacc[qb][dt], 0, 0, 0);
        }
      }
      __builtin_amdgcn_s_setprio(0);
    }
    cur ^= 1;
  }

  // epilogue: every C-row of lacc holds the full row-sum for q=lr
  float l_i[2] = {lacc[0][0], lacc[1][0]};

  if (md == 0) {
    #pragma unroll
    for (int qb = 0; qb < 2; qb++) {
      const float invl = __builtin_amdgcn_rcpf(l_i[qb]);
      const size_t orow = (size_t)(b * T_SEQ + q0 + qb * 16 + lr) * D_MODEL + h * D_HEAD;
      #pragma unroll
      for (int dt = 0; dt < 4; dt++) {
        us4 o;
        #pragma unroll
        for (int i = 0; i < 4; i++) o[i] = f2bf(oacc[qb][dt][i] * invl);
        *(us4*)&Out[orow + dt * 16 + quad * 4] = o;
      }
    }
  } else {
    const int s = md - 1;
    const int p = (bh * 56 + (qg - 8)) * 2 + s;
    unsigned short* Op = opart_ptr(OpA, OpB, p);
    if (quad == 0) {
      Lpart[(p * 2 + 0) * 16 + lr] = l_i[0];
      Lpart[(p * 2 + 1) * 16 + lr] = l_i[1];
    }
    #pragma unroll
    for (int qb = 0; qb < 2; qb++) {
      #pragma unroll
      for (int dt = 0; dt < 4; dt++) {
        us4 o;
        #pragma unroll
        for (int i = 0; i < 4; i++) o[i] = f2bf(oacc[qb][dt][i]);
        *(us4*)&Op[(size_t)(((qb * 4 + dt) * 64) + lane) * 4] = o;
      }
    }
  }
}

// ---------------------------------------------------------------------------
// Merge 2 split partials per (bh, qg in [8,64)): O=(O0+O1)/(l0+l1).
// ---------------------------------------------------------------------------
__global__ __launch_bounds__(64) void flash_reduce(
    unsigned short* __restrict__ OpA, unsigned short* __restrict__ OpB,
    const float* __restrict__ Lpart, unsigned short* __restrict__ Out)
{
  const int bh  = blockIdx.x;
  const int qgr = blockIdx.y;          // qg = 8 + qgr, qgr in [0,56)
  const int q0  = (8 + qgr) * 32;
  const int b   = bh >> 4;
  const int h   = bh & 15;
  const int lane = threadIdx.x;
  const int lr   = lane & 15;
  const int quad = lane >> 4;

  const int item = bh * 56 + qgr;
  const int p0 = item * 2, p1 = item * 2 + 1;
  const unsigned short* O0 = opart_ptr(OpA, OpB, p0);
  const unsigned short* O1 = opart_ptr(OpA, OpB, p1);

  #pragma unroll
  for (int qb = 0; qb < 2; qb++) {
    const float l0 = Lpart[(p0 * 2 + qb) * 16 + lr];
    const float l1 = Lpart[(p1 * 2 + qb) * 16 + lr];
    const float invL = __builtin_amdgcn_rcpf(l0 + l1);
    const size_t orow = (size_t)(b * T_SEQ + q0 + qb * 16 + lr) * D_MODEL + h * D_HEAD;
    #pragma unroll
    for (int dt = 0; dt < 4; dt++) {
      us4 o0 = *(const us4*)&O0[(size_t)(((qb * 4 + dt) * 64) + lane) * 4];
      us4 o1 = *(const us4*)&O1[(size_t)(((qb * 4 + dt) * 64) + lane) * 4];
      us4 o;
      #pragma unroll
      for (int i = 0; i < 4; i++)
        o[i] = f2bf((bf2f(o0[i]) + bf2f(o1[i])) * invL);
      *(us4*)&Out[orow + dt * 16 + quad * 4] = o;
    }
  }
}

// ---------------------------------------------------------------------------
extern "C" void kernel_launch(void* const* d_in, const int* in_sizes, int n_in,
                              void* d_out, int out_size, void* d_ws, size_t ws_size,
                              hipStream_t stream) {
  (void)in_sizes; (void)n_in; (void)out_size; (void)ws_size;

  const float* x  = (const float*)d_in[0];
  const float* wq = (const float*)d_in[1];
  const float* bq = (const float*)d_in[2];
  const float* wk = (const float*)d_in[3];
  const float* bk = (const float*)d_in[4];
  const float* wv = (const float*)d_in[5];
  const float* bv = (const float*)d_in[6];
  const float* wo = (const float*)d_in[7];
  const float* bo = (const float*)d_in[8];
  float* out = (float*)d_out;

  const int M = B_SZ * T_SEQ;   // 4096
  const int N = D_MODEL;        // 1024
  const int K = D_MODEL;        // 1024
  const size_t MN = (size_t)M * N;     // 4M elems
  const size_t WN = (size_t)N * N;     // 1M elems

  // ws layout (bf16 elems): 50 MiB total
  unsigned short* wt    = (unsigned short*)d_ws;   // 4x[N,K] frag-major 8 MiB
  unsigned short* xb    = wt + 4 * WN;             // [M,K]              8 MiB
  unsigned short* qkv   = xb + MN;                 // q,k [bh,T,64]     16 MiB
  unsigned short* qb    = qkv;
  unsigned short* kb    = qkv + MN;
  unsigned short* vT    = qkv + 2 * MN;            // [bh,64,T]          8 MiB
  unsigned short* attnb = vT + MN;                 // [M,N]              8 MiB
  float* Lpart = (float*)(attnb + MN);             // 448 KiB used (1 MiB slot)
  // Opart split-region: wt[0..3WN) (frag-major wq/wk/wv dead after qkv_gemm,
  // 6 MiB) then xb (dead after qkv_gemm, 8 MiB): 3584 partials x 4 KiB.

  conv_all<<<dim3(32, 32, 8), dim3(256), 0, stream>>>(x, wq, wk, wv, wo, wt, xb);

  qkv_gemm<<<dim3(M / 128, 24), dim3(256), 0, stream>>>(xb, wt, bq, bk, bv, qkv, vT);

  flash_part<<<dim3(B_SZ * N_HEADS, 30), dim3(256), 0, stream>>>(
      qb, kb, vT, attnb, wt, xb, Lpart);
  flash_reduce<<<dim3(B_SZ * N_HEADS, 56), dim3(64), 0, stream>>>(
      wt, xb, Lpart, attnb);

  mfma_gemm<<<dim3(M / 128, N / 64), dim3(256), 0, stream>>>(attnb, wt + 3 * WN, bo, out, M, N, K);
}

// Round 10
// 183.748 us; speedup vs baseline: 1.0931x; 1.0931x over previous
//
#include <hip/hip_runtime.h>
#include <math.h>

#define D_MODEL 1024
#define N_HEADS 16
#define D_HEAD  64
#define B_SZ    2
#define T_SEQ   2048
#define WN_ELEMS (1024u * 1024u)

typedef short bf16x8 __attribute__((ext_vector_type(8)));
typedef short bf16x4 __attribute__((ext_vector_type(4)));
typedef float f32x4  __attribute__((ext_vector_type(4)));
typedef unsigned short us4 __attribute__((ext_vector_type(4)));

// fp32 -> bf16 (RNE)
__device__ __forceinline__ unsigned short f2bf(float f) {
  union { float f; unsigned u; } v; v.f = f;
  unsigned r = v.u + 0x7FFFu + ((v.u >> 16) & 1u);
  return (unsigned short)(r >> 16);
}
// bf16 -> fp32
__device__ __forceinline__ float bf2f(unsigned short s) {
  union { unsigned u; float f; } v; v.u = ((unsigned)s) << 16;
  return v.f;
}
// pack two fp32 -> bf16x2 (RTZ) in one v_perm_b32
__device__ __forceinline__ unsigned pack2_rtz(float lo, float hi) {
  union { float f; unsigned u; } a, b; a.f = hi; b.f = lo;
  return __builtin_amdgcn_perm(a.u, b.u, 0x07060302u);
}

// async global->LDS, 16B per lane. LDS dest = wave-uniform base + lane*16.
__device__ __forceinline__ void async_copy16(const unsigned short* g, unsigned short* l) {
  __builtin_amdgcn_global_load_lds(
      (__attribute__((address_space(1))) void*)(g),
      (__attribute__((address_space(3))) void*)(l), 16, 0, 0);
}

// Fragment-major W layout: for feature row n, contraction col k:
//   fb=n>>5, mi=(n>>4)&1, lr=n&15, kt=k>>6, hf=(k>>5)&1, quad=(k>>3)&3, e=k&7
//   idx = ((fb*16+kt)*4 + (mi*2+hf))*512 + (quad*16+lr)*8 + e
// -> a wave's MFMA fragment load is ONE fully-coalesced 1KB read.

// Opart split-region: p-th 4KB partial lives in wt[0..3WN) (dead after
// qkv_gemm) for p < 1536, else in xb (dead after qkv_gemm).
__device__ __forceinline__ unsigned short* opart_ptr(
    unsigned short* wtd, unsigned short* xbd, int p) {
  const size_t off = (size_t)p * 2048;
  const size_t RA  = (size_t)3 * 1024 * 1024;   // 3WN elems (6 MiB)
  return (off < RA) ? (wtd + off) : (xbd + (off - RA));
}

// ---------------------------------------------------------------------------
// Fused converts. grid (32,32,8): z<4 -> W[z] fp32[K,N] -> wt bf16
// FRAGMENT-MAJOR; z>=4 -> x fp32 -> bf16 rows.
// R10: frag-major write phase re-decoded for COALESCED stores. Each 32k x
// 32n transpose tile = two contiguous 512-elem pieces (mi=0,1) at fixed
// (fb,kt,hf); thread tid owns flat elems [f,f+4) of piece mi=tid>>7 ->
// 8B/thread, 128 threads = 1KB contiguous (R7's widx-scatter was 16B @
// 256B stride = 25% write sectoring, ~+5us).
// ---------------------------------------------------------------------------
__global__ __launch_bounds__(256) void conv_all(
    const float* __restrict__ x,
    const float* __restrict__ wq, const float* __restrict__ wk,
    const float* __restrict__ wv, const float* __restrict__ wo,
    unsigned short* __restrict__ wt, unsigned short* __restrict__ xb)
{
  const int z = blockIdx.z;
  if (z < 4) {
    const float* W = (z == 0) ? wq : (z == 1) ? wk : (z == 2) ? wv : wo;
    unsigned short* O = wt + (size_t)z * WN_ELEMS;
    __shared__ float t[32][33];
    const int tx = threadIdx.x & 31, ty = threadIdx.x >> 5;
    const int kb = blockIdx.x * 32, nb = blockIdx.y * 32;
    #pragma unroll
    for (int i = 0; i < 4; i++)
      t[ty + i * 8][tx] = W[(size_t)(kb + ty + i * 8) * D_MODEL + nb + tx];
    __syncthreads();
    // coalesced frag-major write: piece (fb,kt,mi,hf), flat=(quad*16+lr)*8+e
    const int tid = threadIdx.x;
    const int mi  = tid >> 7;            // 0..1
    const int f   = (tid & 127) * 4;     // flat base in [0,512)
    const int qd  = f >> 7;              // quad
    const int lrr = (f >> 3) & 15;       // lr
    const int e0  = f & 7;               // 0 or 4
    const int kt  = kb >> 6, hf = (kb >> 5) & 1, fbn = nb >> 5;
    us4 o;
    #pragma unroll
    for (int j = 0; j < 4; j++)
      o[j] = f2bf(t[qd * 8 + e0 + j][mi * 16 + lrr]);
    *(us4*)&O[((size_t)(fbn * 16 + kt) * 4 + (mi * 2 + hf)) * 512 + f] = o;
  } else {
    const int row = (z - 4) * 1024 + blockIdx.y * 32 + (threadIdx.x >> 3);
    const int col = blockIdx.x * 32 + (threadIdx.x & 7) * 4;
    float4 v = *(const float4*)&x[(size_t)row * D_MODEL + col];
    us4 o = { f2bf(v.x), f2bf(v.y), f2bf(v.z), f2bf(v.w) };
    *(us4*)&xb[(size_t)row * D_MODEL + col] = o;
  }
}

// ---------------------------------------------------------------------------
// Fused QKV GEMM (R7 exact, 43.0us measured): 128(token) x 64(feature)
// tiles, grid (32,48) = 1536 blocks. x LDS-staged dbuf (shared operand);
// W fragments straight global->VGPR from the fragment-major layout
// (coalesced 1KB wave loads), register-dbuf via a 2-step unrolled pipeline.
// mid = col0>>10 (0=q,1=k,2=v), block-uniform.
// NOTE: Q is pre-scaled by 0.125*log2(e) here so flash softmax is exp2(s).
// ---------------------------------------------------------------------------
#define BKg 64
#define NTg (D_MODEL / BKg)   /* 16 K-steps */
#define QSCALE 0.180336879f   /* 0.125 * log2(e) */

__global__ __launch_bounds__(256) void qkv_gemm(
    const unsigned short* __restrict__ A, const unsigned short* __restrict__ Bt,
    const float* __restrict__ bq, const float* __restrict__ bk,
    const float* __restrict__ bv, unsigned short* __restrict__ qkv,
    unsigned short* __restrict__ vT)
{
  __shared__ unsigned short As[2][128 * BKg];   // x tiles: 2x16 KB

  const int tid  = threadIdx.x;
  const int wv   = tid >> 6;
  const int lane = tid & 63;
  const int lr   = lane & 15;
  const int quad = lane >> 4;
  const int wm   = wv >> 1;
  const int wn   = wv & 1;
  const int row0 = blockIdx.x * 128;   // tokens
  const int col0 = blockIdx.y * 64;    // global feature col in [0,3072)
  const int K = D_MODEL;

  const int mid = col0 >> 10;                       // 0=q,1=k,2=v
  const float* bias = (mid == 0) ? bq : (mid == 1) ? bk : bv;

  f32x4 acc[8];
  #pragma unroll
  for (int i = 0; i < 8; i++) acc[i] = (f32x4){0.f, 0.f, 0.f, 0.f};

  auto stageA = [&](int buf, int k0) {
    #pragma unroll
    for (int it = 0; it < 4; it++) {
      const int gg = wv * 256 + it * 64 + lane;
      const int r  = gg >> 3;
      const int gc = ((gg & 7) ^ (r & 7)) * 8;
      async_copy16(A + (size_t)(row0 + r) * K + k0 + gc,
                   &As[buf][(size_t)(wv * 256 + it * 64) * 8]);
    }
  };

  // W fragment base: q/k -> W is A-operand, rows by wm; v -> B-operand, by wn.
  const int wsel = (mid == 2) ? wn : wm;
  const int fb   = ((col0 & 1023) >> 5) + wsel;
  const unsigned short* Wp =
      Bt + (size_t)mid * WN_ELEMS + (size_t)fb * (16 * 2048) + lane * 8;

  auto loadW = [&](int kt, bf16x8 (&W)[2][2]) {
    #pragma unroll
    for (int mi = 0; mi < 2; mi++)
      #pragma unroll
      for (int hf = 0; hf < 2; hf++)
        W[mi][hf] = *(const bf16x8*)&Wp[((size_t)kt * 4 + mi * 2 + hf) * 512];
  };

  // x fragment row group: q/k -> by wn (x is B-operand); v -> by wm.
  const int xrow = (mid == 2) ? wm : wn;

  bf16x8 Wc[2][2], Wn[2][2];
  loadW(0, Wc);
  stageA(0, 0);
  int cur = 0;

  auto kstep = [&](int t, bf16x8 (&Wuse)[2][2], bf16x8 (&Wpre)[2][2]) {
    __syncthreads();                      // x tile t visible in buffer cur

    // 1) x frag ds_reads of tile t
    bf16x8 xF[4][2];
    #pragma unroll
    for (int hf = 0; hf < 2; hf++) {
      const int kc = ((hf * 4 + quad) ^ (lr & 7)) * 8;
      #pragma unroll
      for (int ni = 0; ni < 4; ni++)
        xF[ni][hf] = *(const bf16x8*)&As[cur][(xrow * 64 + ni * 16 + lr) * BKg + kc];
    }

    // 2) prefetch tile t+1: x -> LDS (other buffer), W -> regs (other bank)
    if (t + 1 < NTg) {
      stageA(cur ^ 1, (t + 1) * BKg);
      loadW(t + 1, Wpre);
    }

    // 3) MFMA with Wuse (already resident)
    if (mid == 2) {
      // A=x (tokens), B=W (features): acc[mi*2+ni], mi 0..3 tok, ni 0..1 feat
      #pragma unroll
      for (int hf = 0; hf < 2; hf++)
        #pragma unroll
        for (int mi = 0; mi < 4; mi++)
          #pragma unroll
          for (int ni = 0; ni < 2; ni++)
            acc[mi * 2 + ni] = __builtin_amdgcn_mfma_f32_16x16x32_bf16(
                xF[mi][hf], Wuse[ni][hf], acc[mi * 2 + ni], 0, 0, 0);
    } else {
      // A=W (features), B=x (tokens): acc[mi*4+ni], mi 0..1 feat, ni 0..3 tok
      #pragma unroll
      for (int hf = 0; hf < 2; hf++)
        #pragma unroll
        for (int mi = 0; mi < 2; mi++)
          #pragma unroll
          for (int ni = 0; ni < 4; ni++)
            acc[mi * 4 + ni] = __builtin_amdgcn_mfma_f32_16x16x32_bf16(
                Wuse[mi][hf], xF[ni][hf], acc[mi * 4 + ni], 0, 0, 0);
    }
    cur ^= 1;
  };

  #pragma unroll 1
  for (int t = 0; t < NTg; t += 2) {      // 2-step pipeline: no W reg copies
    kstep(t,     Wc, Wn);
    kstep(t + 1, Wn, Wc);
  }

  if (mid == 2) {
    // C rows = tokens, cols = features; vT[(b*16+h)*64+d][t], us4 over t
    #pragma unroll
    for (int ni = 0; ni < 2; ni++) {
      const int nn = (col0 & 1023) + wn * 32 + ni * 16 + lr;
      const float bv_ = bias[nn];
      const int h = nn >> 6, d = nn & 63;
      #pragma unroll
      for (int mi = 0; mi < 4; mi++) {
        const int t0_ = row0 + wm * 64 + mi * 16 + quad * 4;
        const int b = t0_ >> 11, tl = t0_ & 2047;
        us4 o;
        #pragma unroll
        for (int i = 0; i < 4; i++) o[i] = f2bf(acc[mi * 2 + ni][i] + bv_);
        *(us4*)&vT[((size_t)(b * N_HEADS + h) * D_HEAD + d) * T_SEQ + tl] = o;
      }
    }
  } else {
    // C^T rows = features (reg i -> f+i), cols = tokens; dst[bh][t][d], us4 over d
    unsigned short* dst = qkv + (size_t)mid * (4096u * 1024u);
    const float qs = (mid == 0) ? QSCALE : 1.0f;   // pre-scale Q for exp2 softmax
    #pragma unroll
    for (int ni = 0; ni < 4; ni++) {
      const int t = row0 + wn * 64 + ni * 16 + lr;
      const int b = t >> 11, tl = t & 2047;
      #pragma unroll
      for (int mi = 0; mi < 2; mi++) {
        const int f = (col0 & 1023) + wm * 32 + mi * 16 + quad * 4;
        const int h = f >> 6, d = f & 63;
        const float4 b4 = *(const float4*)&bias[f];
        us4 o;
        o[0] = f2bf((acc[mi * 4 + ni][0] + b4.x) * qs);
        o[1] = f2bf((acc[mi * 4 + ni][1] + b4.y) * qs);
        o[2] = f2bf((acc[mi * 4 + ni][2] + b4.z) * qs);
        o[3] = f2bf((acc[mi * 4 + ni][3] + b4.w) * qs);
        *(us4*)&dst[((size_t)(b * N_HEADS + h) * T_SEQ + tl) * D_HEAD + d] = o;
      }
    }
  }
}

// ---------------------------------------------------------------------------
// bf16 MFMA GEMM (O-projection): C = A[M,K] @ W^T + bias[N], fp32 out.
// W (wo) is fragment-major. x LDS dbuf, W global->VGPR coalesced, 2-step
// register pipeline. 128x64 tile -> grid (32,16). (R7 exact)
// ---------------------------------------------------------------------------
__global__ __launch_bounds__(256) void mfma_gemm(
    const unsigned short* __restrict__ A, const unsigned short* __restrict__ Bt,
    const float* __restrict__ bias, float* __restrict__ C,
    int M, int N, int K)
{
  __shared__ unsigned short As[2][128 * BKg];   // 2x16 KB

  const int tid  = threadIdx.x;
  const int wv   = tid >> 6;
  const int lane = tid & 63;
  const int lr   = lane & 15;
  const int quad = lane >> 4;
  const int wm   = wv >> 1;
  const int wn   = wv & 1;
  const int row0 = blockIdx.x * 128;
  const int col0 = blockIdx.y * 64;

  f32x4 acc[4][2];
  #pragma unroll
  for (int mi = 0; mi < 4; mi++)
    #pragma unroll
    for (int ni = 0; ni < 2; ni++) acc[mi][ni] = (f32x4){0.f, 0.f, 0.f, 0.f};

  auto stageA = [&](int buf, int k0) {
    #pragma unroll
    for (int it = 0; it < 4; it++) {
      const int gg = wv * 256 + it * 64 + lane;
      const int r  = gg >> 3;
      const int gc = ((gg & 7) ^ (r & 7)) * 8;
      async_copy16(A + (size_t)(row0 + r) * K + k0 + gc,
                   &As[buf][(size_t)(wv * 256 + it * 64) * 8]);
    }
  };

  const int fb = (col0 >> 5) + wn;
  const unsigned short* Wp = Bt + (size_t)fb * (16 * 2048) + lane * 8;
  auto loadW = [&](int kt, bf16x8 (&W)[2][2]) {
    #pragma unroll
    for (int ni = 0; ni < 2; ni++)
      #pragma unroll
      for (int hf = 0; hf < 2; hf++)
        W[ni][hf] = *(const bf16x8*)&Wp[((size_t)kt * 4 + ni * 2 + hf) * 512];
  };

  const int NT = K / BKg;
  bf16x8 Wc[2][2], Wn[2][2];
  loadW(0, Wc);
  stageA(0, 0);
  int cur = 0;

  auto kstep = [&](int t, bf16x8 (&Wuse)[2][2], bf16x8 (&Wpre)[2][2]) {
    __syncthreads();

    bf16x8 aF[4][2];
    #pragma unroll
    for (int hf = 0; hf < 2; hf++) {
      const int kc = ((hf * 4 + quad) ^ (lr & 7)) * 8;
      #pragma unroll
      for (int mi = 0; mi < 4; mi++)
        aF[mi][hf] = *(const bf16x8*)&As[cur][(wm * 64 + mi * 16 + lr) * BKg + kc];
    }

    if (t + 1 < NT) {
      stageA(cur ^ 1, (t + 1) * BKg);
      loadW(t + 1, Wpre);
    }

    #pragma unroll
    for (int hf = 0; hf < 2; hf++)
      #pragma unroll
      for (int mi = 0; mi < 4; mi++)
        #pragma unroll
        for (int ni = 0; ni < 2; ni++)
          acc[mi][ni] = __builtin_amdgcn_mfma_f32_16x16x32_bf16(
              aF[mi][hf], Wuse[ni][hf], acc[mi][ni], 0, 0, 0);
    cur ^= 1;
  };

  #pragma unroll 1
  for (int t = 0; t < NT; t += 2) {
    kstep(t,     Wc, Wn);
    kstep(t + 1, Wn, Wc);
  }

  #pragma unroll
  for (int ni = 0; ni < 2; ni++) {
    const int n = col0 + wn * 32 + ni * 16 + lr;
    const float bv = bias[n];
    #pragma unroll
    for (int mi = 0; mi < 4; mi++) {
      #pragma unroll
      for (int i = 0; i < 4; i++) {
        const int m = row0 + wm * 64 + mi * 16 + quad * 4 + i;
        C[(size_t)m * N + n] = acc[mi][ni][i] + bv;
      }
    }
  }
}

// ---------------------------------------------------------------------------
// LDS-staged S^T flash attention, scale-free softmax (causal), split-KV.
// (unchanged from R7)
// ---------------------------------------------------------------------------
__global__ __launch_bounds__(256) void flash_part(
    const unsigned short* __restrict__ Q, const unsigned short* __restrict__ K,
    const unsigned short* __restrict__ Vt, unsigned short* __restrict__ Out,
    unsigned short* __restrict__ OpA, unsigned short* __restrict__ OpB,
    float* __restrict__ Lpart)
{
  const int bh = blockIdx.x;              // 0..31
  const int y  = blockIdx.y;              // 0..29
  int g, md;                              // md: 0 direct, 1 split-s0, 2 split-s1
  if (y < 28) { g = 15 - (y >> 1); md = 1 + (y & 1); }
  else        { g = 29 - y; md = 0; }     // y=28 -> g=1, y=29 -> g=0

  const int b  = bh >> 4;
  const int h  = bh & 15;

  const unsigned short* Qb = Q  + (size_t)bh * T_SEQ * D_HEAD;
  const unsigned short* Kb = K  + (size_t)bh * T_SEQ * D_HEAD;
  const unsigned short* Vb = Vt + (size_t)bh * D_HEAD * T_SEQ;   // [d][t]

  __shared__ __align__(16) unsigned short Ks[2][64 * 64];
  __shared__ __align__(16) unsigned short Vs[2][64 * 64];

  const int tid  = threadIdx.x;
  const int wv4  = tid >> 6;
  const int lane = tid & 63;
  const int lr   = lane & 15;
  const int quad = lane >> 4;

  const int qg      = 4 * g + wv4;
  const int q0      = qg * 32;
  const int my_full = 2 * g + 1 + (wv4 >> 1);                  // true last tile + 1
  const int tstart  = (md == 2) ? (g + 1) : 0;
  const int bend    = (md == 1) ? (g + 1) : (2 * g + 2);       // block staging range
  const int my_end  = (md == 1) ? (g + 1) : my_full;           // wave compute range

  const int cbase = (tid & ~63);
  const int rr = tid >> 3;                               // 0..31
  const int gcf = ((tid & 7) ^ (rr & 7)) * 8;            // const over it
  const unsigned short* kp0 = Kb + (size_t)rr * D_HEAD + gcf;
  const unsigned short* vp0 = Vb + (size_t)rr * T_SEQ + gcf;

  auto stage = [&](int buf, int tile) {
    const unsigned short* kt = kp0 + (size_t)tile * (64 * D_HEAD);
    const unsigned short* vt = vp0 + (size_t)tile * 64;
    async_copy16(kt,                    &Ks[buf][(size_t)cbase * 8]);
    async_copy16(kt + 32 * D_HEAD,      &Ks[buf][(size_t)(256 + cbase) * 8]);
    async_copy16(vt,                    &Vs[buf][(size_t)cbase * 8]);
    async_copy16(vt + (size_t)32 * T_SEQ, &Vs[buf][(size_t)(256 + cbase) * 8]);
  };

  // Q as B-operand (loop-invariant)
  bf16x8 bQ[2][2];
  #pragma unroll
  for (int qb = 0; qb < 2; qb++)
    #pragma unroll
    for (int kh = 0; kh < 2; kh++)
      bQ[qb][kh] = *(const bf16x8*)&Qb[(size_t)(q0 + qb * 16 + lr) * D_HEAD + kh * 32 + quad * 8];

  f32x4 oacc[2][4];
  #pragma unroll
  for (int qb = 0; qb < 2; qb++)
    #pragma unroll
    for (int dt = 0; dt < 4; dt++) oacc[qb][dt] = (f32x4){0.f, 0.f, 0.f, 0.f};
  f32x4 lacc[2] = {(f32x4){0.f, 0.f, 0.f, 0.f}, (f32x4){0.f, 0.f, 0.f, 0.f}};

  const bf16x4 vONE = {(short)0x3F80, (short)0x3F80, (short)0x3F80, (short)0x3F80};

  int cur = 0;
  stage(0, tstart);

  for (int j = tstart; j < bend; j++) {
    __syncthreads();                        // staged tile j visible
    const bool act = (j < my_end);          // wave-uniform
    const unsigned short* KsB = &Ks[cur][0];
    const unsigned short* VsB = &Vs[cur][0];
    const int kv0 = j * 64;

    // 1) fragment ds_reads of tile j
    bf16x8 aK[4][2];
    bf16x4 aV[4][4];
    if (act) {
      #pragma unroll
      for (int nt = 0; nt < 4; nt++) {
        const int row = nt * 16 + lr;
        #pragma unroll
        for (int kh = 0; kh < 2; kh++) {
          const int sc = (kh * 4 + quad) ^ (row & 7);
          aK[nt][kh] = *(const bf16x8*)&KsB[row * 64 + sc * 8];
        }
      }
      #pragma unroll
      for (int dt = 0; dt < 4; dt++) {
        const int row = dt * 16 + lr;
        #pragma unroll
        for (int ks = 0; ks < 4; ks++) {
          const int sc = (ks * 2 + (quad >> 1)) ^ (row & 7);
          aV[dt][ks] = *(const bf16x4*)&VsB[row * 64 + sc * 8 + (quad & 1) * 4];
        }
      }
    }

    // 2) prefetch next tile into the other buffer (overlaps with compute)
    if (j + 1 < bend) stage(cur ^ 1, j + 1);

    // 3) compute
    if (act) {
      f32x4 sacc[2][4];
      __builtin_amdgcn_s_setprio(1);
      #pragma unroll
      for (int nt = 0; nt < 4; nt++) {
        #pragma unroll
        for (int qb = 0; qb < 2; qb++) {
          f32x4 c = (f32x4){0.f, 0.f, 0.f, 0.f};
          c = __builtin_amdgcn_mfma_f32_16x16x32_bf16(aK[nt][0], bQ[qb][0], c, 0, 0, 0);
          c = __builtin_amdgcn_mfma_f32_16x16x32_bf16(aK[nt][1], bQ[qb][1], c, 0, 0, 0);
          sacc[qb][nt] = c;
        }
      }
      __builtin_amdgcn_s_setprio(0);

      // scale-free softmax: p = exp2(s); Q pre-scaled, no max subtraction
      const bool diag = (j == my_full - 1);
      bf16x4 bP[2][4];
      #pragma unroll
      for (int qb = 0; qb < 2; qb++) {
        if (diag) {
          const int qcol = q0 + qb * 16 + lr;
          #pragma unroll
          for (int nt = 0; nt < 4; nt++)
            #pragma unroll
            for (int i = 0; i < 4; i++)
              if (kv0 + nt * 16 + quad * 4 + i > qcol) sacc[qb][nt][i] = -INFINITY;
        }
        #pragma unroll
        for (int nt = 0; nt < 4; nt++) {
          float p[4];
          #pragma unroll
          for (int i = 0; i < 4; i++)
            p[i] = __builtin_amdgcn_exp2f(sacc[qb][nt][i]);
          union { unsigned u[2]; bf16x4 v; } pk;
          pk.u[0] = pack2_rtz(p[0], p[1]);
          pk.u[1] = pack2_rtz(p[2], p[3]);
          bP[qb][nt] = pk.v;
        }
      }

      // PV + row-sum(l) on the MFMA pipe (ones-fragment matmul)
      __builtin_amdgcn_s_setprio(1);
      #pragma unroll
      for (int ks = 0; ks < 4; ks++) {
        #pragma unroll
        for (int qb = 0; qb < 2; qb++) {
          lacc[qb] = __builtin_amdgcn_mfma_f32_16x16x16bf16_1k(
              vONE, bP[qb][ks], lacc[qb], 0, 0, 0);
          #pragma unroll
          for (int dt = 0; dt < 4; dt++)
            oacc[qb][dt] = __builtin_amdgcn_mfma_f32_16x16x16bf16_1k(
                aV[dt][ks], bP[qb][ks], oacc[qb][dt], 0, 0, 0);
        }
      }
      __builtin_amdgcn_s_setprio(0);
    }
    cur ^= 1;
  }

  // epilogue: every C-row of lacc holds the full row-sum for q=lr
  float l_i[2] = {lacc[0][0], lacc[1][0]};

  if (md == 0) {
    #pragma unroll
    for (int qb = 0; qb < 2; qb++) {
      const float invl = __builtin_amdgcn_rcpf(l_i[qb]);
      const size_t orow = (size_t)(b * T_SEQ + q0 + qb * 16 + lr) * D_MODEL + h * D_HEAD;
      #pragma unroll
      for (int dt = 0; dt < 4; dt++) {
        us4 o;
        #pragma unroll
        for (int i = 0; i < 4; i++) o[i] = f2bf(oacc[qb][dt][i] * invl);
        *(us4*)&Out[orow + dt * 16 + quad * 4] = o;
      }
    }
  } else {
    const int s = md - 1;
    const int p = (bh * 56 + (qg - 8)) * 2 + s;
    unsigned short* Op = opart_ptr(OpA, OpB, p);
    if (quad == 0) {
      Lpart[(p * 2 + 0) * 16 + lr] = l_i[0];
      Lpart[(p * 2 + 1) * 16 + lr] = l_i[1];
    }
    #pragma unroll
    for (int qb = 0; qb < 2; qb++) {
      #pragma unroll
      for (int dt = 0; dt < 4; dt++) {
        us4 o;
        #pragma unroll
        for (int i = 0; i < 4; i++) o[i] = f2bf(oacc[qb][dt][i]);
        *(us4*)&Op[(size_t)(((qb * 4 + dt) * 64) + lane) * 4] = o;
      }
    }
  }
}

// ---------------------------------------------------------------------------
// Merge 2 split partials per (bh, qg in [8,64)): O=(O0+O1)/(l0+l1).
// ---------------------------------------------------------------------------
__global__ __launch_bounds__(64) void flash_reduce(
    unsigned short* __restrict__ OpA, unsigned short* __restrict__ OpB,
    const float* __restrict__ Lpart, unsigned short* __restrict__ Out)
{
  const int bh  = blockIdx.x;
  const int qgr = blockIdx.y;          // qg = 8 + qgr, qgr in [0,56)
  const int q0  = (8 + qgr) * 32;
  const int b   = bh >> 4;
  const int h   = bh & 15;
  const int lane = threadIdx.x;
  const int lr   = lane & 15;
  const int quad = lane >> 4;

  const int item = bh * 56 + qgr;
  const int p0 = item * 2, p1 = item * 2 + 1;
  const unsigned short* O0 = opart_ptr(OpA, OpB, p0);
  const unsigned short* O1 = opart_ptr(OpA, OpB, p1);

  #pragma unroll
  for (int qb = 0; qb < 2; qb++) {
    const float l0 = Lpart[(p0 * 2 + qb) * 16 + lr];
    const float l1 = Lpart[(p1 * 2 + qb) * 16 + lr];
    const float invL = __builtin_amdgcn_rcpf(l0 + l1);
    const size_t orow = (size_t)(b * T_SEQ + q0 + qb * 16 + lr) * D_MODEL + h * D_HEAD;
    #pragma unroll
    for (int dt = 0; dt < 4; dt++) {
      us4 o0 = *(const us4*)&O0[(size_t)(((qb * 4 + dt) * 64) + lane) * 4];
      us4 o1 = *(const us4*)&O1[(size_t)(((qb * 4 + dt) * 64) + lane) * 4];
      us4 o;
      #pragma unroll
      for (int i = 0; i < 4; i++)
        o[i] = f2bf((bf2f(o0[i]) + bf2f(o1[i])) * invL);
      *(us4*)&Out[orow + dt * 16 + quad * 4] = o;
    }
  }
}

// ---------------------------------------------------------------------------
extern "C" void kernel_launch(void* const* d_in, const int* in_sizes, int n_in,
                              void* d_out, int out_size, void* d_ws, size_t ws_size,
                              hipStream_t stream) {
  (void)in_sizes; (void)n_in; (void)out_size; (void)ws_size;

  const float* x  = (const float*)d_in[0];
  const float* wq = (const float*)d_in[1];
  const float* bq = (const float*)d_in[2];
  const float* wk = (const float*)d_in[3];
  const float* bk = (const float*)d_in[4];
  const float* wv = (const float*)d_in[5];
  const float* bv = (const float*)d_in[6];
  const float* wo = (const float*)d_in[7];
  const float* bo = (const float*)d_in[8];
  float* out = (float*)d_out;

  const int M = B_SZ * T_SEQ;   // 4096
  const int N = D_MODEL;        // 1024
  const int K = D_MODEL;        // 1024
  const size_t MN = (size_t)M * N;     // 4M elems
  const size_t WN = (size_t)N * N;     // 1M elems

  // ws layout (bf16 elems): 50 MiB total
  unsigned short* wt    = (unsigned short*)d_ws;   // 4x[N,K] frag-major 8 MiB
  unsigned short* xb    = wt + 4 * WN;             // [M,K]              8 MiB
  unsigned short* qkv   = xb + MN;                 // q,k [bh,T,64]     16 MiB
  unsigned short* qb    = qkv;
  unsigned short* kb    = qkv + MN;
  unsigned short* vT    = qkv + 2 * MN;            // [bh,64,T]          8 MiB
  unsigned short* attnb = vT + MN;                 // [M,N]              8 MiB
  float* Lpart = (float*)(attnb + MN);             // 448 KiB used (1 MiB slot)
  // Opart split-region: wt[0..3WN) (frag-major wq/wk/wv dead after qkv_gemm,
  // 6 MiB) then xb (dead after qkv_gemm, 8 MiB): 3584 partials x 4 KiB.

  conv_all<<<dim3(32, 32, 8), dim3(256), 0, stream>>>(x, wq, wk, wv, wo, wt, xb);

  qkv_gemm<<<dim3(M / 128, 48), dim3(256), 0, stream>>>(xb, wt, bq, bk, bv, qkv, vT);

  flash_part<<<dim3(B_SZ * N_HEADS, 30), dim3(256), 0, stream>>>(
      qb, kb, vT, attnb, wt, xb, Lpart);
  flash_reduce<<<dim3(B_SZ * N_HEADS, 56), dim3(64), 0, stream>>>(
      wt, xb, Lpart, attnb);

  mfma_gemm<<<dim3(M / 128, N / 64), dim3(256), 0, stream>>>(attnb, wt + 3 * WN, bo, out, M, N, K);
}